// Round 1
// baseline (80.443 us; speedup 1.0000x reference)
//
#include <hip/hip_runtime.h>

#define NN 1024
#define BB 64

// ---------------------------------------------------------------------------
// Kernel 1: per-(batch, row-chunk) partial diagonal sums.
// Each wave has a private LDS accumulator (lane -> d stride-1: conflict-free).
__global__ __launch_bounds__(256) void diag_partial(const float* __restrict__ attns,
                                                    float* __restrict__ partial,
                                                    int chunks, int rows_per_chunk) {
    __shared__ float acc[4][NN];   // 16 KB, one accumulator per wave
    const int c = blockIdx.x;
    const int b = blockIdx.y;
    const int tid = threadIdx.x;
    const int wid = tid >> 6;
    const int lane = tid & 63;

    for (int d = tid; d < NN; d += 256) {
        acc[0][d] = 0.f; acc[1][d] = 0.f; acc[2][d] = 0.f; acc[3][d] = 0.f;
    }
    __syncthreads();

    const int i0 = c * rows_per_chunk;
    const float* base = attns + (size_t)b * NN * NN;
    float* a = acc[wid];

    for (int i = i0 + wid; i < i0 + rows_per_chunk; i += 4) {
        const float* row = base + (size_t)i * NN;
        // j from i (upper triangle only); d = j - i = lane + 64*m : per-lane distinct
        for (int j = i + lane; j < NN; j += 64) {
            a[j - i] += row[j];
        }
    }
    __syncthreads();

    float* outp = partial + ((size_t)b * chunks + c) * NN;
    for (int d = tid; d < NN; d += 256)
        outp[d] = acc[0][d] + acc[1][d] + acc[2][d] + acc[3][d];
}

// ---------------------------------------------------------------------------
// Kernel 2: reduce chunk partials -> waves[b][d] = sum / (N - d)
__global__ __launch_bounds__(256) void reduce_waves(const float* __restrict__ partial,
                                                    float* __restrict__ waves,
                                                    int chunks) {
    const int idx = blockIdx.x * blockDim.x + threadIdx.x;
    if (idx >= BB * NN) return;
    const int b = idx >> 10;
    const int d = idx & (NN - 1);
    float s = 0.f;
    for (int c = 0; c < chunks; ++c)
        s += partial[((size_t)b * chunks + c) * NN + d];
    waves[idx] = s / (float)(NN - d);
}

// ---------------------------------------------------------------------------
// Kernel 3: direct DFT, bins k = 1..512 split into 4 groups of 128 per batch.
// Each thread owns one k; phase via exact integer t = (k*d) & 1023.
__global__ __launch_bounds__(128) void dft_part(const float* __restrict__ waves,
                                                float* __restrict__ kparts) {
    __shared__ float w[NN];
    __shared__ float redmax[2], redsum[2];
    const int split = blockIdx.x & 3;
    const int b = blockIdx.x >> 2;
    const int tid = threadIdx.x;

    const float* wr = waves + (size_t)b * NN;
    for (int d = tid; d < NN; d += 128) w[d] = wr[d];
    __syncthreads();

    const int k = 1 + split * 128 + tid;           // k in [1, 512]
    const float C = 6.283185307179586f / 1024.0f;  // 2*pi/N

    float re0 = 0.f, re1 = 0.f, re2 = 0.f, re3 = 0.f;
    float im0 = 0.f, im1 = 0.f, im2 = 0.f, im3 = 0.f;

    for (int d = 0; d < NN; d += 4) {
        int t0 = (k * (d + 0)) & (NN - 1);
        int t1 = (k * (d + 1)) & (NN - 1);
        int t2 = (k * (d + 2)) & (NN - 1);
        int t3 = (k * (d + 3)) & (NN - 1);
        float s0, c0, s1, c1, s2, c2, s3, c3;
        __sincosf((float)t0 * C, &s0, &c0);
        __sincosf((float)t1 * C, &s1, &c1);
        __sincosf((float)t2 * C, &s2, &c2);
        __sincosf((float)t3 * C, &s3, &c3);
        const float w0 = w[d + 0], w1 = w[d + 1], w2 = w[d + 2], w3 = w[d + 3];
        re0 = fmaf(w0, c0, re0);  im0 = fmaf(w0, -s0, im0);
        re1 = fmaf(w1, c1, re1);  im1 = fmaf(w1, -s1, im1);
        re2 = fmaf(w2, c2, re2);  im2 = fmaf(w2, -s2, im2);
        re3 = fmaf(w3, c3, re3);  im3 = fmaf(w3, -s3, im3);
    }
    const float re = (re0 + re1) + (re2 + re3);
    const float im = (im0 + im1) + (im2 + im3);
    float spec = sqrtf(re * re + im * im);

    // reduce max & sum across the 128 threads (2 waves)
    float mx = spec, sm = spec;
    for (int off = 32; off; off >>= 1) {
        mx = fmaxf(mx, __shfl_xor(mx, off, 64));
        sm += __shfl_xor(sm, off, 64);
    }
    const int wid = tid >> 6, lane = tid & 63;
    if (lane == 0) { redmax[wid] = mx; redsum[wid] = sm; }
    __syncthreads();
    if (tid == 0) {
        kparts[((size_t)b * 4 + split) * 2 + 0] = fmaxf(redmax[0], redmax[1]);
        kparts[((size_t)b * 4 + split) * 2 + 1] = redsum[0] + redsum[1];
    }
}

// ---------------------------------------------------------------------------
// Kernel 4: judgement per batch, mean over batches.
__global__ __launch_bounds__(64) void finalize(const float* __restrict__ kparts,
                                               float* __restrict__ out) {
    const int lane = threadIdx.x;  // one lane per batch, 64 = one wave
    float M = 0.f, S = 0.f;
    for (int s = 0; s < 4; ++s) {
        M = fmaxf(M, kparts[((size_t)lane * 4 + s) * 2 + 0]);
        S += kparts[((size_t)lane * 4 + s) * 2 + 1];
    }
    float j = 1.0f - M / S;
    for (int off = 32; off; off >>= 1) j += __shfl_xor(j, off, 64);
    if (lane == 0) out[0] = j * (1.0f / 64.0f);
}

// ---------------------------------------------------------------------------
extern "C" void kernel_launch(void* const* d_in, const int* in_sizes, int n_in,
                              void* d_out, int out_size, void* d_ws, size_t ws_size,
                              hipStream_t stream) {
    const float* attns = (const float*)d_in[0];
    float* out = (float*)d_out;

    // workspace layout: [partial: B*chunks*N] [waves: B*N] [kparts: B*4*2]
    int chunks = 16;
    auto need = [](int c) {
        return (size_t)BB * c * NN * 4 + (size_t)BB * NN * 4 + (size_t)BB * 4 * 2 * 4;
    };
    while (chunks > 1 && need(chunks) > ws_size) chunks >>= 1;

    float* partial = (float*)d_ws;
    float* waves   = partial + (size_t)BB * chunks * NN;
    float* kparts  = waves + (size_t)BB * NN;
    const int rpc = NN / chunks;

    diag_partial<<<dim3(chunks, BB), 256, 0, stream>>>(attns, partial, chunks, rpc);
    reduce_waves<<<(BB * NN) / 256, 256, 0, stream>>>(partial, waves, chunks);
    dft_part<<<BB * 4, 128, 0, stream>>>(waves, kparts);
    finalize<<<1, 64, 0, stream>>>(kparts, out);
}

// Round 2
// 53.545 us; speedup vs baseline: 1.5023x; 1.5023x over previous
//
#include <hip/hip_runtime.h>

#define NN 1024
#define BB 64
#define CHUNKS 16

// ---------------------------------------------------------------------------
// Kernel 1: register-accumulated partial diagonal sums.
// Block c handles rows i ≡ c (mod 16)  => r = i&3 constant per block.
// With jbase = i - r, lane v = lane + 64*it loads float4 at column jbase+4v,
// contributing to d = 4v - r + comp — a FIXED (lane,it,comp)->d mapping, so
// each lane accumulates in 4 float4 registers across all its rows.
__global__ __launch_bounds__(256) void diag_partial(const float* __restrict__ attns,
                                                    float* __restrict__ partial) {
    __shared__ float lds[4][1032];  // per-wave dump region (+8 pad for d+r reads)
    const int c = blockIdx.x;       // 0..15
    const int b = blockIdx.y;
    const int tid = threadIdx.x;
    const int wid = tid >> 6, lane = tid & 63;
    const int r = c & 3;

    float4 acc[4];
    acc[0] = make_float4(0.f, 0.f, 0.f, 0.f);
    acc[1] = acc[0]; acc[2] = acc[0]; acc[3] = acc[0];

    const float* base = attns + (size_t)b * NN * NN;

    for (int t = 0; t < 16; ++t) {
        const int i = c + 16 * wid + 64 * t;      // i ≡ c (mod 16), i&3 == r
        const int jbase = i - r;                  // 4-aligned
        const int nvec = (NN - jbase) >> 2;
        const float4* f4 = (const float4*)(base + (size_t)i * NN + jbase);
#pragma unroll
        for (int it = 0; it < 4; ++it) {
            const int v = lane + 64 * it;
            if (v < nvec) {
                float4 x = f4[v];
                if (it == 0 && lane == 0) {       // head mask: j < i (d < 0)
                    if (r > 0) x.x = 0.f;
                    if (r > 1) x.y = 0.f;
                    if (r > 2) x.z = 0.f;
                }
                acc[it].x += x.x; acc[it].y += x.y;
                acc[it].z += x.z; acc[it].w += x.w;
            }
        }
    }

    // dump registers: lds[wid][4*lane + 256*it + comp] = acc ; bijective onto [0,1024)
    float4* lrow = (float4*)lds[wid];
#pragma unroll
    for (int it = 0; it < 4; ++it) lrow[lane + 64 * it] = acc[it];
    if (tid < 32) lds[tid >> 3][1024 + (tid & 7)] = 0.f;   // zero the +pad tail
    __syncthreads();

    // partial[b][c][d] = sum over waves of lds[w][d + r]
    float* outp = partial + ((size_t)b * CHUNKS + c) * NN;
    for (int d = tid; d < NN; d += 256)
        outp[d] = (lds[0][d + r] + lds[1][d + r]) + (lds[2][d + r] + lds[3][d + r]);
}

// ---------------------------------------------------------------------------
// Kernel 2: reduce chunk partials -> waves[b][d] = sum / (N - d)
__global__ __launch_bounds__(256) void reduce_waves(const float* __restrict__ partial,
                                                    float* __restrict__ waves) {
    const int idx = blockIdx.x * blockDim.x + threadIdx.x;
    const int b = idx >> 10;
    const int d = idx & (NN - 1);
    float s = 0.f;
    for (int c = 0; c < CHUNKS; ++c)
        s += partial[((size_t)b * CHUNKS + c) * NN + d];
    waves[idx] = s / (float)(NN - d);
}

// ---------------------------------------------------------------------------
// Kernel 3: direct DFT, bins k = 1..512. Grid (b, ksplit=4), 512 threads.
// Thread: k = 1 + ks*128 + (tid>>2), d-phase = tid&3 (4-way d split per k).
__global__ __launch_bounds__(512) void dft_part(const float* __restrict__ waves,
                                                float* __restrict__ kparts) {
    __shared__ float w[NN];
    __shared__ float redmax[8], redsum[8];
    const int ks = blockIdx.x & 3;
    const int b = blockIdx.x >> 2;
    const int tid = threadIdx.x;

    const float* wr = waves + (size_t)b * NN;
    for (int d = tid; d < NN; d += 512) w[d] = wr[d];
    __syncthreads();

    const int k = 1 + ks * 128 + (tid >> 2);
    const int dp = tid & 3;
    const float C = 6.283185307179586f / 1024.0f;

    float re = 0.f, im = 0.f;
    for (int d = dp; d < NN; d += 4) {
        const int t = (k * d) & (NN - 1);          // exact integer phase
        float s, cc;
        __sincosf((float)t * C, &s, &cc);
        const float wv = w[d];
        re = fmaf(wv, cc, re);
        im = fmaf(wv, -s, im);
    }
    // combine the 4 d-phases (lanes tid^1, tid^2 are the same k)
    re += __shfl_xor(re, 1, 64); re += __shfl_xor(re, 2, 64);
    im += __shfl_xor(im, 1, 64); im += __shfl_xor(im, 2, 64);
    const float spec = sqrtf(re * re + im * im);

    // wave reduce: max over k, sum over k (count each k once)
    float mx = spec;
    float sm = ((tid & 3) == 0) ? spec : 0.f;
    for (int off = 4; off < 64; off <<= 1) {
        mx = fmaxf(mx, __shfl_xor(mx, off, 64));
        sm += __shfl_xor(sm, off, 64);
    }
    const int wid = tid >> 6, lane = tid & 63;
    if (lane == 0) { redmax[wid] = mx; redsum[wid] = sm; }
    __syncthreads();
    if (tid == 0) {
        float M = redmax[0], S = redsum[0];
        for (int i = 1; i < 8; ++i) { M = fmaxf(M, redmax[i]); S += redsum[i]; }
        kparts[((size_t)b * 4 + ks) * 2 + 0] = M;
        kparts[((size_t)b * 4 + ks) * 2 + 1] = S;
    }
}

// ---------------------------------------------------------------------------
// Kernel 4: judgement per batch, mean over batches.
__global__ __launch_bounds__(64) void finalize(const float* __restrict__ kparts,
                                               float* __restrict__ out) {
    const int lane = threadIdx.x;   // one lane per batch
    float M = 0.f, S = 0.f;
    for (int s = 0; s < 4; ++s) {
        M = fmaxf(M, kparts[((size_t)lane * 4 + s) * 2 + 0]);
        S += kparts[((size_t)lane * 4 + s) * 2 + 1];
    }
    float j = 1.0f - M / S;
    for (int off = 32; off; off >>= 1) j += __shfl_xor(j, off, 64);
    if (lane == 0) out[0] = j * (1.0f / 64.0f);
}

// ---------------------------------------------------------------------------
extern "C" void kernel_launch(void* const* d_in, const int* in_sizes, int n_in,
                              void* d_out, int out_size, void* d_ws, size_t ws_size,
                              hipStream_t stream) {
    const float* attns = (const float*)d_in[0];
    float* out = (float*)d_out;

    // workspace: [partial: B*CHUNKS*N] [waves: B*N] [kparts: B*4*2]
    float* partial = (float*)d_ws;
    float* waves   = partial + (size_t)BB * CHUNKS * NN;
    float* kparts  = waves + (size_t)BB * NN;

    diag_partial<<<dim3(CHUNKS, BB), 256, 0, stream>>>(attns, partial);
    reduce_waves<<<(BB * NN) / 256, 256, 0, stream>>>(partial, waves);
    dft_part<<<BB * 4, 512, 0, stream>>>(waves, kparts);
    finalize<<<1, 64, 0, stream>>>(kparts, out);
}

// Round 3
// 49.501 us; speedup vs baseline: 1.6251x; 1.0817x over previous
//
#include <hip/hip_runtime.h>

#define NN 1024
#define BB 64
#define CHUNKS 16

// ---------------------------------------------------------------------------
// Kernel 1: register-accumulated partial diagonal sums.
// Block c handles rows i ≡ c (mod 16) => r = i&3 constant per block.
// With jbase = i - r, lane v = lane + 64*it loads float4 at column jbase+4v,
// contributing to d = 4v - r + comp — a FIXED (lane,it,comp)->d mapping.
// Loads are UNCONDITIONAL (clamped address + cndmask zero) and separated from
// the adds so 8 global_load_dwordx4 stay in flight per wave (no per-load
// vmcnt(0) serialization — the R1 bottleneck).
__global__ __launch_bounds__(256) void diag_partial(const float* __restrict__ attns,
                                                    float* __restrict__ partial) {
    __shared__ float lds[4][1032];  // per-wave dump region (+8 pad for d+r reads)
    const int c = blockIdx.x;       // 0..15
    const int b = blockIdx.y;
    const int tid = threadIdx.x;
    const int wid = tid >> 6, lane = tid & 63;
    const int r = c & 3;

    float4 acc[4];
    acc[0] = make_float4(0.f, 0.f, 0.f, 0.f);
    acc[1] = acc[0]; acc[2] = acc[0]; acc[3] = acc[0];

    const float* base = attns + (size_t)b * NN * NN;

#pragma unroll 2
    for (int t = 0; t < 16; ++t) {
        const int i = c + 16 * wid + 64 * t;      // wave-uniform row index
        const int jbase = i - r;                  // 4-aligned, wave-uniform
        const int nvec = (NN - jbase) >> 2;       // wave-uniform, >= 1
        const float4* f4 = (const float4*)(base + (size_t)i * NN + jbase);

        float4 x[4];
#pragma unroll
        for (int it = 0; it < 4; ++it) {
            const int v = lane + 64 * it;
            const int vc = v < nvec - 1 ? v : nvec - 1;   // clamp: stay in-row
            x[it] = f4[vc];                                // unconditional load
        }
        // zero out-of-range lanes (v >= nvec) and the head (j < i)
#pragma unroll
        for (int it = 0; it < 4; ++it) {
            const int v = lane + 64 * it;
            const bool ok = v < nvec;
            x[it].x = ok ? x[it].x : 0.f;
            x[it].y = ok ? x[it].y : 0.f;
            x[it].z = ok ? x[it].z : 0.f;
            x[it].w = ok ? x[it].w : 0.f;
        }
        if (lane == 0) {
            if (r > 0) x[0].x = 0.f;
            if (r > 1) x[0].y = 0.f;
            if (r > 2) x[0].z = 0.f;
        }
#pragma unroll
        for (int it = 0; it < 4; ++it) {
            acc[it].x += x[it].x; acc[it].y += x[it].y;
            acc[it].z += x[it].z; acc[it].w += x[it].w;
        }
    }

    // dump registers: lds[wid][4*(lane+64*it) + comp] = acc ; bijective on [0,1024)
    float4* lrow = (float4*)lds[wid];
#pragma unroll
    for (int it = 0; it < 4; ++it) lrow[lane + 64 * it] = acc[it];
    if (tid < 32) lds[tid >> 3][1024 + (tid & 7)] = 0.f;   // zero the +pad tail
    __syncthreads();

    // partial[b][c][d] = sum over waves of lds[w][d + r]
    float* outp = partial + ((size_t)b * CHUNKS + c) * NN;
    for (int d = tid; d < NN; d += 256)
        outp[d] = (lds[0][d + r] + lds[1][d + r]) + (lds[2][d + r] + lds[3][d + r]);
}

// ---------------------------------------------------------------------------
// Kernel 2: reduce chunk partials -> waves[b][d] = sum / (N - d)
__global__ __launch_bounds__(256) void reduce_waves(const float* __restrict__ partial,
                                                    float* __restrict__ waves) {
    const int idx = blockIdx.x * blockDim.x + threadIdx.x;
    const int b = idx >> 10;
    const int d = idx & (NN - 1);
    float s = 0.f;
    for (int c = 0; c < CHUNKS; ++c)
        s += partial[((size_t)b * CHUNKS + c) * NN + d];
    waves[idx] = s / (float)(NN - d);
}

// ---------------------------------------------------------------------------
// Kernel 3: direct DFT with LDS twiddle table, bins k = 1..512.
// Grid (b, ks=8), 512 threads. Thread: k = 1 + ks*64 + (tid>>3), d-phase tid&7.
// Incremental exact integer phase: t_{n+1} = (t_n + 8k) & 1023.
__global__ __launch_bounds__(512) void dft_part(const float* __restrict__ waves,
                                                float* __restrict__ kparts) {
    __shared__ float w[NN];
    __shared__ float2 twc[NN];      // (cos, -sin)
    __shared__ float redmax[8], redsum[8];
    const int ks = blockIdx.x & 7;
    const int b = blockIdx.x >> 3;
    const int tid = threadIdx.x;

    const float* wr = waves + (size_t)b * NN;
    const float C = 6.283185307179586f / 1024.0f;
    for (int t = tid; t < NN; t += 512) {
        w[t] = wr[t];
        const float ph = (float)t * C;
        twc[t] = make_float2(cosf(ph), -sinf(ph));
    }
    __syncthreads();

    const int k = 1 + ks * 64 + (tid >> 3);
    const int dp = tid & 7;
    const int kstep = (k << 3) & (NN - 1);

    float re = 0.f, im = 0.f;
    int t = (k * dp) & (NN - 1);
#pragma unroll 4
    for (int d = dp; d < NN; d += 8) {
        const float2 tw = twc[t];
        const float wv = w[d];
        re = fmaf(wv, tw.x, re);
        im = fmaf(wv, tw.y, im);
        t = (t + kstep) & (NN - 1);
    }
    // combine the 8 d-phases (same k within each 8-lane group)
    re += __shfl_xor(re, 1, 64); re += __shfl_xor(re, 2, 64); re += __shfl_xor(re, 4, 64);
    im += __shfl_xor(im, 1, 64); im += __shfl_xor(im, 2, 64); im += __shfl_xor(im, 4, 64);
    const float spec = sqrtf(re * re + im * im);

    // wave reduce: max over k, sum over k (count each k once)
    float mx = spec;
    float sm = ((tid & 7) == 0) ? spec : 0.f;
    for (int off = 8; off < 64; off <<= 1) {
        mx = fmaxf(mx, __shfl_xor(mx, off, 64));
        sm += __shfl_xor(sm, off, 64);
    }
    const int wid = tid >> 6, lane = tid & 63;
    if (lane == 0) { redmax[wid] = mx; redsum[wid] = sm; }
    __syncthreads();
    if (tid == 0) {
        float M = redmax[0], S = redsum[0];
        for (int i = 1; i < 8; ++i) { M = fmaxf(M, redmax[i]); S += redsum[i]; }
        kparts[((size_t)b * 8 + ks) * 2 + 0] = M;
        kparts[((size_t)b * 8 + ks) * 2 + 1] = S;
    }
}

// ---------------------------------------------------------------------------
// Kernel 4: judgement per batch, mean over batches.
__global__ __launch_bounds__(64) void finalize(const float* __restrict__ kparts,
                                               float* __restrict__ out) {
    const int lane = threadIdx.x;   // one lane per batch
    float M = 0.f, S = 0.f;
    for (int s = 0; s < 8; ++s) {
        M = fmaxf(M, kparts[((size_t)lane * 8 + s) * 2 + 0]);
        S += kparts[((size_t)lane * 8 + s) * 2 + 1];
    }
    float j = 1.0f - M / S;
    for (int off = 32; off; off >>= 1) j += __shfl_xor(j, off, 64);
    if (lane == 0) out[0] = j * (1.0f / 64.0f);
}

// ---------------------------------------------------------------------------
extern "C" void kernel_launch(void* const* d_in, const int* in_sizes, int n_in,
                              void* d_out, int out_size, void* d_ws, size_t ws_size,
                              hipStream_t stream) {
    const float* attns = (const float*)d_in[0];
    float* out = (float*)d_out;

    // workspace: [partial: B*CHUNKS*N] [waves: B*N] [kparts: B*8*2]
    float* partial = (float*)d_ws;
    float* waves   = partial + (size_t)BB * CHUNKS * NN;
    float* kparts  = waves + (size_t)BB * NN;

    diag_partial<<<dim3(CHUNKS, BB), 256, 0, stream>>>(attns, partial);
    reduce_waves<<<(BB * NN) / 256, 256, 0, stream>>>(partial, waves);
    dft_part<<<BB * 8, 512, 0, stream>>>(waves, kparts);
    finalize<<<1, 64, 0, stream>>>(kparts, out);
}